// Round 1
// baseline (66.901 us; speedup 1.0000x reference)
//
#include <hip/hip_runtime.h>

#define N_TOT 8192
#define BSZ   4096
#define DIM   256

typedef __attribute__((ext_vector_type(8))) short bf16x8;
typedef __attribute__((ext_vector_type(4))) float f32x4;

__device__ __forceinline__ unsigned short f2bf(float f) {
    unsigned int u = __builtin_bit_cast(unsigned int, f);
    u = (u + 0x7fffu + ((u >> 16) & 1u)) >> 16;   // round-to-nearest-even
    return (unsigned short)u;
}
__device__ __forceinline__ float bf2f(unsigned short h) {
    unsigned int u = ((unsigned int)h) << 16;
    return __builtin_bit_cast(float, u);
}

// ---------------------------------------------------------------------------
// Kernel 1: L2-normalize rows of zi/zj, write concatenated bf16 matrix zb[8192][256]
// One wave per row; each lane handles 4 floats (float4).
// ---------------------------------------------------------------------------
__global__ __launch_bounds__(256) void norm_kernel(const float* __restrict__ zi,
                                                   const float* __restrict__ zj,
                                                   unsigned short* __restrict__ zb) {
    const int wid  = threadIdx.x >> 6;
    const int lane = threadIdx.x & 63;
    const int row  = blockIdx.x * 4 + wid;          // 0..8191
    const float* src = (row < BSZ) ? (zi + (size_t)row * DIM)
                                   : (zj + (size_t)(row - BSZ) * DIM);
    float4 v = ((const float4*)src)[lane];
    float ss = v.x * v.x + v.y * v.y + v.z * v.z + v.w * v.w;
    #pragma unroll
    for (int off = 1; off < 64; off <<= 1) ss += __shfl_xor(ss, off);
    float inv = 1.0f / fmaxf(sqrtf(ss), 1e-12f);
    ushort4 o;
    o.x = f2bf(v.x * inv);
    o.y = f2bf(v.y * inv);
    o.z = f2bf(v.z * inv);
    o.w = f2bf(v.w * inv);
    ((ushort4*)(zb + (size_t)row * DIM))[lane] = o;
}

// ---------------------------------------------------------------------------
// Kernel 2: fused Z*Z^T -> exp(2x) -> partial row sums (diagonal excluded).
// BM=BN=128, BK=64, 256 threads = 4 waves (2x2), 64x64 per wave,
// mfma_f32_16x16x32_bf16, XOR-swizzled LDS (byte ^= (row&7)<<4).
// partial[slot][row], slot = bj*2 + wc  (128 slots x 8192 rows).
// ---------------------------------------------------------------------------
__global__ __launch_bounds__(256, 2) void sim_kernel(const unsigned short* __restrict__ zb,
                                                     float* __restrict__ partial) {
    __shared__ alignas(16) unsigned short As[128 * 64];
    __shared__ alignas(16) unsigned short Bs[128 * 64];

    const int t    = threadIdx.x;
    const int lane = t & 63;
    const int wid  = t >> 6;
    const int wr   = wid >> 1;     // 0..1
    const int wc   = wid & 1;      // 0..1
    const int bi   = blockIdx.x >> 6;
    const int bj   = blockIdx.x & 63;
    const int row0 = bi * 128;
    const int col0 = bj * 128;

    f32x4 acc[4][4];
    #pragma unroll
    for (int m = 0; m < 4; m++)
        #pragma unroll
        for (int n = 0; n < 4; n++) acc[m][n] = (f32x4){0.f, 0.f, 0.f, 0.f};

    for (int kt = 0; kt < 4; ++kt) {
        // ---- stage 128x64 bf16 tiles of A(rows) and B(cols) into LDS ----
        uint4 ra[4], rb[4];
        #pragma unroll
        for (int i = 0; i < 4; i++) {
            const int e = i * 256 + t;      // 16B-chunk index 0..1023
            const int r = e >> 3;           // row in tile 0..127
            const int q = e & 7;            // chunk within row 0..7
            ra[i] = *((const uint4*)(zb + ((size_t)(row0 + r) * DIM + kt * 64)) + q);
            rb[i] = *((const uint4*)(zb + ((size_t)(col0 + r) * DIM + kt * 64)) + q);
        }
        #pragma unroll
        for (int i = 0; i < 4; i++) {
            const int e  = i * 256 + t;
            const int r  = e >> 3;
            const int q  = e & 7;
            const int wq = q ^ (r & 7);     // XOR swizzle (bank-conflict-free)
            *(uint4*)((char*)As + r * 128 + wq * 16) = ra[i];
            *(uint4*)((char*)Bs + r * 128 + wq * 16) = rb[i];
        }
        __syncthreads();

        // ---- compute: 2 k-slices of 32 ----
        #pragma unroll
        for (int kk = 0; kk < 2; kk++) {
            bf16x8 af[4], bfr[4];
            #pragma unroll
            for (int m = 0; m < 4; m++) {
                const int rr = wr * 64 + m * 16 + (lane & 15);
                const int q  = kk * 4 + (lane >> 4);
                af[m] = *(const bf16x8*)((const char*)As + rr * 128 + ((q ^ (rr & 7)) << 4));
            }
            #pragma unroll
            for (int n = 0; n < 4; n++) {
                const int rr = wc * 64 + n * 16 + (lane & 15);
                const int q  = kk * 4 + (lane >> 4);
                bfr[n] = *(const bf16x8*)((const char*)Bs + rr * 128 + ((q ^ (rr & 7)) << 4));
            }
            #pragma unroll
            for (int m = 0; m < 4; m++)
                #pragma unroll
                for (int n = 0; n < 4; n++)
                    acc[m][n] = __builtin_amdgcn_mfma_f32_16x16x32_bf16(af[m], bfr[n], acc[m][n], 0, 0, 0);
        }
        __syncthreads();
    }

    // ---- epilogue: exp(2x), zero diagonal, per-row sums over this wave's 64 cols
    float rsum[4][4];
    #pragma unroll
    for (int m = 0; m < 4; m++)
        #pragma unroll
        for (int j = 0; j < 4; j++) rsum[m][j] = 0.f;

    const int colbase = col0 + wc * 64 + (lane & 15);
    const int rowbase = row0 + wr * 64 + ((lane >> 4) << 2);
    #pragma unroll
    for (int m = 0; m < 4; m++) {
        #pragma unroll
        for (int n = 0; n < 4; n++) {
            const int colg = colbase + n * 16;
            #pragma unroll
            for (int j = 0; j < 4; j++) {
                const int rowg = rowbase + m * 16 + j;
                const float e = (rowg == colg) ? 0.0f : __expf(2.0f * acc[m][n][j]);
                rsum[m][j] += e;
            }
        }
    }
    // reduce across the 16 lanes holding different cols (lane&15 varies)
    #pragma unroll
    for (int m = 0; m < 4; m++) {
        #pragma unroll
        for (int j = 0; j < 4; j++) {
            float s = rsum[m][j];
            s += __shfl_xor(s, 1);
            s += __shfl_xor(s, 2);
            s += __shfl_xor(s, 4);
            s += __shfl_xor(s, 8);
            rsum[m][j] = s;
        }
    }
    if ((lane & 15) == 0) {
        const int slot = bj * 2 + wc;
        float* dst = partial + (size_t)slot * N_TOT;
        #pragma unroll
        for (int m = 0; m < 4; m++)
            #pragma unroll
            for (int j = 0; j < 4; j++)
                dst[rowbase + m * 16 + j] = rsum[m][j];
    }
}

// ---------------------------------------------------------------------------
// Kernel 3: per-row sum of 128 partials -> log(negsum+eps); block partial sums.
// ---------------------------------------------------------------------------
__global__ __launch_bounds__(256) void rowlog_kernel(const float* __restrict__ partial,
                                                     float* __restrict__ logPart) {
    const int row = blockIdx.x * 256 + threadIdx.x;   // 32 blocks
    float s = 0.f;
    #pragma unroll 8
    for (int p = 0; p < 128; p++) s += partial[(size_t)p * N_TOT + row];
    float v = logf(s + 1e-8f);
    #pragma unroll
    for (int off = 1; off < 64; off <<= 1) v += __shfl_xor(v, off);
    __shared__ float red[4];
    const int lane = threadIdx.x & 63, wid = threadIdx.x >> 6;
    if (lane == 0) red[wid] = v;
    __syncthreads();
    if (threadIdx.x == 0) logPart[blockIdx.x] = red[0] + red[1] + red[2] + red[3];
}

// ---------------------------------------------------------------------------
// Kernel 4: positive-pair dots  dot(zb[i], zb[i+BSZ]); one wave per row.
// ---------------------------------------------------------------------------
__global__ __launch_bounds__(256) void pos_kernel(const unsigned short* __restrict__ zb,
                                                  float* __restrict__ posPart) {
    const int wid  = threadIdx.x >> 6;
    const int lane = threadIdx.x & 63;
    const int row  = blockIdx.x * 4 + wid;            // 0..4095
    const ushort4 a = ((const ushort4*)(zb + (size_t)row * DIM))[lane];
    const ushort4 b = ((const ushort4*)(zb + (size_t)(row + BSZ) * DIM))[lane];
    float d = bf2f(a.x) * bf2f(b.x) + bf2f(a.y) * bf2f(b.y) +
              bf2f(a.z) * bf2f(b.z) + bf2f(a.w) * bf2f(b.w);
    #pragma unroll
    for (int off = 1; off < 64; off <<= 1) d += __shfl_xor(d, off);
    __shared__ float red[4];
    if (lane == 0) red[wid] = d;
    __syncthreads();
    if (threadIdx.x == 0) posPart[blockIdx.x] = red[0] + red[1] + red[2] + red[3];
}

// ---------------------------------------------------------------------------
// Kernel 5: final scalar:  loss = mean(log terms) - 2*sum(dots)/BSZ
// ---------------------------------------------------------------------------
__global__ __launch_bounds__(256) void final_kernel(const float* __restrict__ logPart,
                                                    const float* __restrict__ posPart,
                                                    float* __restrict__ out) {
    const int t = threadIdx.x;
    float ps = 0.f;
    for (int i = t; i < 1024; i += 256) ps += posPart[i];
    float ls = (t < 32) ? logPart[t] : 0.f;
    #pragma unroll
    for (int off = 1; off < 64; off <<= 1) {
        ps += __shfl_xor(ps, off);
        ls += __shfl_xor(ls, off);
    }
    __shared__ float redp[4], redl[4];
    const int lane = t & 63, wid = t >> 6;
    if (lane == 0) { redp[wid] = ps; redl[wid] = ls; }
    __syncthreads();
    if (t == 0) {
        const float posSum = redp[0] + redp[1] + redp[2] + redp[3];
        const float logSum = redl[0] + redl[1] + redl[2] + redl[3];
        out[0] = logSum / (float)N_TOT - 2.0f * posSum / (float)BSZ;
    }
}

extern "C" void kernel_launch(void* const* d_in, const int* in_sizes, int n_in,
                              void* d_out, int out_size, void* d_ws, size_t ws_size,
                              hipStream_t stream) {
    const float* zi = (const float*)d_in[0];
    const float* zj = (const float*)d_in[1];
    float* out = (float*)d_out;

    char* ws = (char*)d_ws;
    unsigned short* zb = (unsigned short*)ws;                    // 8192*256*2 = 4 MB
    float* partial     = (float*)(ws + (size_t)(4 << 20));       // 128*8192*4 = 4 MB
    float* logPart     = (float*)(ws + (size_t)(8 << 20));       // 32 floats
    float* posPart     = (float*)(ws + (size_t)(8 << 20) + 4096);// 1024 floats

    norm_kernel<<<2048, 256, 0, stream>>>(zi, zj, zb);
    sim_kernel<<<4096, 256, 0, stream>>>(zb, partial);
    rowlog_kernel<<<32, 256, 0, stream>>>(partial, logPart);
    pos_kernel<<<1024, 256, 0, stream>>>(zb, posPart);
    final_kernel<<<1, 256, 0, stream>>>(logPart, posPart, out);
}

// Round 2
// 51.908 us; speedup vs baseline: 1.2888x; 1.2888x over previous
//
#include <hip/hip_runtime.h>

#define N_TOT 8192
#define BSZ   4096
#define DIM   256

typedef __attribute__((ext_vector_type(8))) short bf16x8;
typedef __attribute__((ext_vector_type(4))) float f32x4;

__device__ __forceinline__ unsigned short f2bf(float f) {
    unsigned int u = __builtin_bit_cast(unsigned int, f);
    u = (u + 0x7fffu + ((u >> 16) & 1u)) >> 16;   // round-to-nearest-even
    return (unsigned short)u;
}

__device__ __forceinline__ void async_copy16(const void* g, void* l) {
    __builtin_amdgcn_global_load_lds((const __attribute__((address_space(1))) void*)g,
                                     (__attribute__((address_space(3))) void*)l,
                                     16, 0, 0);
}

// ---------------------------------------------------------------------------
// Kernel 1: L2-normalize rows of zi/zj -> bf16 zb[8192][256]; fused positive-
// pair dots in fp32. Block = 4 waves: waves 0,1 = zi rows (2 per block),
// waves 2,3 = the matching zj rows. zi waves stash normalized fp32 in LDS;
// zj waves compute the dot.
// ---------------------------------------------------------------------------
__global__ __launch_bounds__(256) void norm_kernel(const float* __restrict__ zi,
                                                   const float* __restrict__ zj,
                                                   unsigned short* __restrict__ zb,
                                                   float* __restrict__ posPart) {
    __shared__ float buf[2][256];
    const int wid  = threadIdx.x >> 6;
    const int lane = threadIdx.x & 63;
    const int pair = blockIdx.x * 2 + (wid & 1);    // 0..4095
    const bool isZj = (wid >= 2);
    const float* src = isZj ? (zj + (size_t)pair * DIM) : (zi + (size_t)pair * DIM);
    float4 v = ((const float4*)src)[lane];
    float ss = v.x * v.x + v.y * v.y + v.z * v.z + v.w * v.w;
    #pragma unroll
    for (int off = 1; off < 64; off <<= 1) ss += __shfl_xor(ss, off);
    float inv = 1.0f / fmaxf(sqrtf(ss), 1e-12f);
    float4 nv = make_float4(v.x * inv, v.y * inv, v.z * inv, v.w * inv);

    const int outRow = isZj ? (pair + BSZ) : pair;
    ushort4 o;
    o.x = f2bf(nv.x); o.y = f2bf(nv.y); o.z = f2bf(nv.z); o.w = f2bf(nv.w);
    ((ushort4*)(zb + (size_t)outRow * DIM))[lane] = o;

    if (!isZj) ((float4*)&buf[wid & 1][0])[lane] = nv;
    __syncthreads();
    if (isZj) {
        float4 a = ((float4*)&buf[wid & 1][0])[lane];
        float d = a.x * nv.x + a.y * nv.y + a.z * nv.z + a.w * nv.w;
        #pragma unroll
        for (int off = 1; off < 64; off <<= 1) d += __shfl_xor(d, off);
        if (lane == 0) posPart[pair] = d;
    }
}

// ---------------------------------------------------------------------------
// Kernel 2: symmetric fused Z*Z^T -> exp(2x) -> partial row AND col sums.
// Only upper-triangular blocks (bi <= bj): 2080 blocks.
// BM=BN=128, BK=64, 4 waves (2x2), 64x64/wave, mfma_f32_16x16x32_bf16.
// Staging: global_load_lds(16B) into linear LDS, XOR swizzle applied on the
// GLOBAL source chunk index (involution) + on the LDS read -> conflict-free.
// partial[slot][row]: row-sums -> slot bj*2+wc (rows of bi-block);
//                     col-sums -> slot bi*2+wr (rows of bj-block, skip if diag).
// ---------------------------------------------------------------------------
__global__ __launch_bounds__(256, 3) void sim_kernel(const unsigned short* __restrict__ zb,
                                                     float* __restrict__ partial) {
    __shared__ alignas(16) unsigned short As[128 * 64];
    __shared__ alignas(16) unsigned short Bs[128 * 64];

    const int t    = threadIdx.x;
    const int lane = t & 63;
    const int wid  = t >> 6;
    const int wr   = wid >> 1;     // 0..1
    const int wc   = wid & 1;      // 0..1

    // decode upper-triangular (bi, bj), bi <= bj, from linear block id
    const int k = blockIdx.x;                       // 0..2079
    int bi = (int)((129.0f - sqrtf(16641.0f - 8.0f * (float)k)) * 0.5f);
    while (bi * 64 - bi * (bi - 1) / 2 > k) bi--;
    while ((bi + 1) * 64 - (bi + 1) * bi / 2 <= k) bi++;
    const int bj = bi + (k - (bi * 64 - bi * (bi - 1) / 2));
    const bool diag = (bi == bj);

    const int row0 = bi * 128;
    const int col0 = bj * 128;

    f32x4 acc[4][4];
    #pragma unroll
    for (int m = 0; m < 4; m++)
        #pragma unroll
        for (int n = 0; n < 4; n++) acc[m][n] = (f32x4){0.f, 0.f, 0.f, 0.f};

    const unsigned short* Bbase = diag ? As : Bs;

    for (int kt = 0; kt < 4; ++kt) {
        // ---- stage via global_load_lds: LDS linear, source chunk pre-swizzled
        #pragma unroll
        for (int i = 0; i < 4; i++) {
            const int e = i * 256 + t;          // linear 16B-chunk index 0..1023
            const int r = e >> 3;               // tile row 0..127
            const int p = e & 7;                // LDS chunk-in-row
            const int sc = p ^ (r & 7);         // swizzled source chunk
            const int ldsOff = (i * 256 + wid * 64) * 8;   // wave-uniform (shorts)
            const unsigned short* ga = zb + (size_t)(row0 + r) * DIM + kt * 64 + sc * 8;
            async_copy16(ga, (void*)(As + ldsOff));
            if (!diag) {
                const unsigned short* gb = zb + (size_t)(col0 + r) * DIM + kt * 64 + sc * 8;
                async_copy16(gb, (void*)(Bs + ldsOff));
            }
        }
        __syncthreads();

        // ---- compute: 2 k-slices of 32
        #pragma unroll
        for (int kk = 0; kk < 2; kk++) {
            bf16x8 af[4], bfr[4];
            #pragma unroll
            for (int m = 0; m < 4; m++) {
                const int rr = wr * 64 + m * 16 + (lane & 15);
                const int q  = kk * 4 + (lane >> 4);
                af[m] = *(const bf16x8*)((const char*)As + rr * 128 + ((q ^ (rr & 7)) << 4));
            }
            #pragma unroll
            for (int n = 0; n < 4; n++) {
                const int rr = wc * 64 + n * 16 + (lane & 15);
                const int q  = kk * 4 + (lane >> 4);
                bfr[n] = *(const bf16x8*)((const char*)Bbase + rr * 128 + ((q ^ (rr & 7)) << 4));
            }
            #pragma unroll
            for (int m = 0; m < 4; m++)
                #pragma unroll
                for (int n = 0; n < 4; n++)
                    acc[m][n] = __builtin_amdgcn_mfma_f32_16x16x32_bf16(af[m], bfr[n], acc[m][n], 0, 0, 0);
        }
        __syncthreads();
    }

    // ---- epilogue: exp(2x); row sums (always) + col sums (off-diag) ----
    float rsum[4][4];
    float csum[4];
    #pragma unroll
    for (int m = 0; m < 4; m++)
        #pragma unroll
        for (int j = 0; j < 4; j++) rsum[m][j] = 0.f;
    #pragma unroll
    for (int n = 0; n < 4; n++) csum[n] = 0.f;

    const int colbase = col0 + wc * 64 + (lane & 15);
    const int rowbase = row0 + wr * 64 + ((lane >> 4) << 2);
    #pragma unroll
    for (int m = 0; m < 4; m++) {
        #pragma unroll
        for (int n = 0; n < 4; n++) {
            const int colg = colbase + n * 16;
            #pragma unroll
            for (int j = 0; j < 4; j++) {
                const int rowg = rowbase + m * 16 + j;
                float e = __expf(2.0f * acc[m][n][j]);
                if (diag && rowg == colg) e = 0.0f;
                rsum[m][j] += e;
                csum[n] += e;
            }
        }
    }

    // row sums: reduce over the 16 col-lanes (lane&15 varies)
    #pragma unroll
    for (int m = 0; m < 4; m++) {
        #pragma unroll
        for (int j = 0; j < 4; j++) {
            float s = rsum[m][j];
            s += __shfl_xor(s, 1);
            s += __shfl_xor(s, 2);
            s += __shfl_xor(s, 4);
            s += __shfl_xor(s, 8);
            rsum[m][j] = s;
        }
    }
    if ((lane & 15) == 0) {
        float* dst = partial + (size_t)(bj * 2 + wc) * N_TOT;
        #pragma unroll
        for (int m = 0; m < 4; m++)
            #pragma unroll
            for (int j = 0; j < 4; j++)
                dst[rowbase + m * 16 + j] = rsum[m][j];
    }

    // col sums: reduce over the 4 row-groups (lane>>4 varies)
    if (!diag) {
        #pragma unroll
        for (int n = 0; n < 4; n++) {
            float s = csum[n];
            s += __shfl_xor(s, 16);
            s += __shfl_xor(s, 32);
            csum[n] = s;
        }
        if (lane < 16) {
            float* dst = partial + (size_t)(bi * 2 + wr) * N_TOT;
            #pragma unroll
            for (int n = 0; n < 4; n++)
                dst[colbase + n * 16] = csum[n];
        }
    }
}

// ---------------------------------------------------------------------------
// Kernel 3: per-row sum of 128 partials -> log(negsum+eps); block partial sums.
// ---------------------------------------------------------------------------
__global__ __launch_bounds__(256) void rowlog_kernel(const float* __restrict__ partial,
                                                     float* __restrict__ logPart) {
    const int row = blockIdx.x * 256 + threadIdx.x;   // 32 blocks
    float s = 0.f;
    #pragma unroll 8
    for (int p = 0; p < 128; p++) s += partial[(size_t)p * N_TOT + row];
    float v = logf(s + 1e-8f);
    #pragma unroll
    for (int off = 1; off < 64; off <<= 1) v += __shfl_xor(v, off);
    __shared__ float red[4];
    const int lane = threadIdx.x & 63, wid = threadIdx.x >> 6;
    if (lane == 0) red[wid] = v;
    __syncthreads();
    if (threadIdx.x == 0) logPart[blockIdx.x] = red[0] + red[1] + red[2] + red[3];
}

// ---------------------------------------------------------------------------
// Kernel 4: final scalar: loss = mean(log terms) - 2*sum(dots)/BSZ
// ---------------------------------------------------------------------------
__global__ __launch_bounds__(256) void final_kernel(const float* __restrict__ logPart,
                                                    const float* __restrict__ posPart,
                                                    float* __restrict__ out) {
    const int t = threadIdx.x;
    float ps = 0.f;
    for (int i = t; i < BSZ; i += 256) ps += posPart[i];
    float ls = (t < 32) ? logPart[t] : 0.f;
    #pragma unroll
    for (int off = 1; off < 64; off <<= 1) {
        ps += __shfl_xor(ps, off);
        ls += __shfl_xor(ls, off);
    }
    __shared__ float redp[4], redl[4];
    const int lane = t & 63, wid = t >> 6;
    if (lane == 0) { redp[wid] = ps; redl[wid] = ls; }
    __syncthreads();
    if (t == 0) {
        const float posSum = redp[0] + redp[1] + redp[2] + redp[3];
        const float logSum = redl[0] + redl[1] + redl[2] + redl[3];
        out[0] = logSum / (float)N_TOT - 2.0f * posSum / (float)BSZ;
    }
}

extern "C" void kernel_launch(void* const* d_in, const int* in_sizes, int n_in,
                              void* d_out, int out_size, void* d_ws, size_t ws_size,
                              hipStream_t stream) {
    const float* zi = (const float*)d_in[0];
    const float* zj = (const float*)d_in[1];
    float* out = (float*)d_out;

    char* ws = (char*)d_ws;
    unsigned short* zb = (unsigned short*)ws;                    // 8192*256*2 = 4 MB
    float* partial     = (float*)(ws + (size_t)(4 << 20));       // 128*8192*4 = 4 MB
    float* logPart     = (float*)(ws + (size_t)(8 << 20));       // 32 floats
    float* posPart     = (float*)(ws + (size_t)(8 << 20) + 4096);// 4096 floats

    norm_kernel<<<2048, 256, 0, stream>>>(zi, zj, zb, posPart);
    sim_kernel<<<2080, 256, 0, stream>>>(zb, partial);
    rowlog_kernel<<<32, 256, 0, stream>>>(partial, logPart);
    final_kernel<<<1, 256, 0, stream>>>(logPart, posPart, out);
}

// Round 3
// 51.233 us; speedup vs baseline: 1.3058x; 1.0132x over previous
//
#include <hip/hip_runtime.h>

#define N_TOT 8192
#define BSZ   4096
#define DIM   256

typedef __attribute__((ext_vector_type(8))) short bf16x8;
typedef __attribute__((ext_vector_type(4))) float f32x4;

__device__ __forceinline__ unsigned short f2bf(float f) {
    unsigned int u = __builtin_bit_cast(unsigned int, f);
    u = (u + 0x7fffu + ((u >> 16) & 1u)) >> 16;   // round-to-nearest-even
    return (unsigned short)u;
}

__device__ __forceinline__ void async_copy16(const void* g, void* l) {
    __builtin_amdgcn_global_load_lds((const __attribute__((address_space(1))) void*)g,
                                     (__attribute__((address_space(3))) void*)l,
                                     16, 0, 0);
}

// ---------------------------------------------------------------------------
// Kernel 1: L2-normalize rows of zi/zj -> bf16 zb[8192][256]; fused positive-
// pair dots in fp32. Waves 0,1 = zi rows; waves 2,3 = matching zj rows.
// ---------------------------------------------------------------------------
__global__ __launch_bounds__(256) void norm_kernel(const float* __restrict__ zi,
                                                   const float* __restrict__ zj,
                                                   unsigned short* __restrict__ zb,
                                                   float* __restrict__ posPart) {
    __shared__ float buf[2][256];
    const int wid  = threadIdx.x >> 6;
    const int lane = threadIdx.x & 63;
    const int pair = blockIdx.x * 2 + (wid & 1);    // 0..4095
    const bool isZj = (wid >= 2);
    const float* src = isZj ? (zj + (size_t)pair * DIM) : (zi + (size_t)pair * DIM);
    float4 v = ((const float4*)src)[lane];
    float ss = v.x * v.x + v.y * v.y + v.z * v.z + v.w * v.w;
    #pragma unroll
    for (int off = 1; off < 64; off <<= 1) ss += __shfl_xor(ss, off);
    float inv = 1.0f / fmaxf(sqrtf(ss), 1e-12f);
    float4 nv = make_float4(v.x * inv, v.y * inv, v.z * inv, v.w * inv);

    const int outRow = isZj ? (pair + BSZ) : pair;
    ushort4 o;
    o.x = f2bf(nv.x); o.y = f2bf(nv.y); o.z = f2bf(nv.z); o.w = f2bf(nv.w);
    ((ushort4*)(zb + (size_t)outRow * DIM))[lane] = o;

    if (!isZj) ((float4*)&buf[wid & 1][0])[lane] = nv;
    __syncthreads();
    if (isZj) {
        float4 a = ((float4*)&buf[wid & 1][0])[lane];
        float d = a.x * nv.x + a.y * nv.y + a.z * nv.z + a.w * nv.w;
        #pragma unroll
        for (int off = 1; off < 64; off <<= 1) d += __shfl_xor(d, off);
        if (lane == 0) posPart[pair] = d;
    }
}

// ---------------------------------------------------------------------------
// Kernel 2: symmetric fused Z*Z^T -> exp(2x) -> partial row AND col sums.
// Upper-triangular blocks only (bi <= bj): 2080 blocks, 128x128 tile, BK=64.
// 2-phase double-buffered pipeline: global_load_lds(16B) prefetch of tile
// kt+1 stays in flight across raw s_barriers (s_waitcnt vmcnt(8), never 0
// mid-loop). XOR swizzle on the GLOBAL source chunk (involution) + on the
// LDS read -> conflict-free ds_read_b128, linear gload_lds destination.
// ---------------------------------------------------------------------------
__global__ __launch_bounds__(256, 2) void sim_kernel(const unsigned short* __restrict__ zb,
                                                     float* __restrict__ partial) {
    __shared__ alignas(16) unsigned short As[2][128 * 64];
    __shared__ alignas(16) unsigned short Bs[2][128 * 64];

    const int t    = threadIdx.x;
    const int lane = t & 63;
    const int wid  = t >> 6;
    const int wr   = wid >> 1;     // 0..1
    const int wc   = wid & 1;      // 0..1

    // decode upper-triangular (bi, bj), bi <= bj, from linear block id
    const int k = blockIdx.x;                       // 0..2079
    int bi = (int)((129.0f - sqrtf(16641.0f - 8.0f * (float)k)) * 0.5f);
    while (bi * 64 - bi * (bi - 1) / 2 > k) bi--;
    while ((bi + 1) * 64 - (bi + 1) * bi / 2 <= k) bi++;
    const int bj = bi + (k - (bi * 64 - bi * (bi - 1) / 2));
    const bool diag = (bi == bj);

    const int row0 = bi * 128;
    const int col0 = bj * 128;

    f32x4 acc[4][4];
    #pragma unroll
    for (int m = 0; m < 4; m++)
        #pragma unroll
        for (int n = 0; n < 4; n++) acc[m][n] = (f32x4){0.f, 0.f, 0.f, 0.f};

    // stage one BK=64 K-tile (A and B) into buffer `b` (8 gload_lds / thread)
    #define STAGE(b, kt) do {                                                   \
        _Pragma("unroll")                                                       \
        for (int i = 0; i < 4; i++) {                                           \
            const int e  = i * 256 + t;        /* 16B-chunk index 0..1023 */    \
            const int r  = e >> 3;             /* tile row 0..127 */            \
            const int p  = e & 7;              /* LDS chunk-in-row */           \
            const int sc = p ^ (r & 7);        /* swizzled source chunk */      \
            const int ldsOff = (i * 256 + wid * 64) * 8;  /* wave-uniform */    \
            async_copy16(zb + (size_t)(row0 + r) * DIM + (kt) * 64 + sc * 8,    \
                         &As[b][ldsOff]);                                       \
            async_copy16(zb + (size_t)(col0 + r) * DIM + (kt) * 64 + sc * 8,    \
                         &Bs[b][ldsOff]);                                       \
        } } while (0)

    STAGE(0, 0);   // prologue

    #pragma unroll
    for (int kt = 0; kt < 4; ++kt) {
        const int cur = kt & 1;
        if (kt < 3) {
            STAGE(cur ^ 1, kt + 1);
            asm volatile("s_waitcnt vmcnt(8)" ::: "memory");  // tile kt landed
        } else {
            asm volatile("s_waitcnt vmcnt(0)" ::: "memory");
        }
        __builtin_amdgcn_sched_barrier(0);
        __builtin_amdgcn_s_barrier();

        #pragma unroll
        for (int kk = 0; kk < 2; kk++) {
            bf16x8 af[4], bfr[4];
            #pragma unroll
            for (int m = 0; m < 4; m++) {
                const int rr = wr * 64 + m * 16 + (lane & 15);
                const int q  = kk * 4 + (lane >> 4);
                af[m] = *(const bf16x8*)((const char*)&As[cur][0] + rr * 128 + ((q ^ (rr & 7)) << 4));
            }
            #pragma unroll
            for (int n = 0; n < 4; n++) {
                const int rr = wc * 64 + n * 16 + (lane & 15);
                const int q  = kk * 4 + (lane >> 4);
                bfr[n] = *(const bf16x8*)((const char*)&Bs[cur][0] + rr * 128 + ((q ^ (rr & 7)) << 4));
            }
            #pragma unroll
            for (int m = 0; m < 4; m++)
                #pragma unroll
                for (int n = 0; n < 4; n++)
                    acc[m][n] = __builtin_amdgcn_mfma_f32_16x16x32_bf16(af[m], bfr[n], acc[m][n], 0, 0, 0);
        }
        __builtin_amdgcn_sched_barrier(0);
        __builtin_amdgcn_s_barrier();   // buf[cur] free for overwrite next iter
    }
    #undef STAGE

    // ---- epilogue: exp(2x); row sums (always) + col sums (off-diag) ----
    float rsum[4][4];
    float csum[4];
    #pragma unroll
    for (int m = 0; m < 4; m++)
        #pragma unroll
        for (int j = 0; j < 4; j++) rsum[m][j] = 0.f;
    #pragma unroll
    for (int n = 0; n < 4; n++) csum[n] = 0.f;

    const int colbase = col0 + wc * 64 + (lane & 15);
    const int rowbase = row0 + wr * 64 + ((lane >> 4) << 2);
    #pragma unroll
    for (int m = 0; m < 4; m++) {
        #pragma unroll
        for (int n = 0; n < 4; n++) {
            const int colg = colbase + n * 16;
            #pragma unroll
            for (int j = 0; j < 4; j++) {
                const int rowg = rowbase + m * 16 + j;
                float e = __expf(2.0f * acc[m][n][j]);
                if (diag && rowg == colg) e = 0.0f;
                rsum[m][j] += e;
                csum[n] += e;
            }
        }
    }

    // row sums: reduce over the 16 col-lanes (lane&15 varies)
    #pragma unroll
    for (int m = 0; m < 4; m++) {
        #pragma unroll
        for (int j = 0; j < 4; j++) {
            float s = rsum[m][j];
            s += __shfl_xor(s, 1);
            s += __shfl_xor(s, 2);
            s += __shfl_xor(s, 4);
            s += __shfl_xor(s, 8);
            rsum[m][j] = s;
        }
    }
    if ((lane & 15) == 0) {
        float* dst = partial + (size_t)(bj * 2 + wc) * N_TOT;
        #pragma unroll
        for (int m = 0; m < 4; m++)
            #pragma unroll
            for (int j = 0; j < 4; j++)
                dst[rowbase + m * 16 + j] = rsum[m][j];
    }

    // col sums: reduce over the 4 row-groups (lane>>4 varies)
    if (!diag) {
        #pragma unroll
        for (int n = 0; n < 4; n++) {
            float s = csum[n];
            s += __shfl_xor(s, 16);
            s += __shfl_xor(s, 32);
            csum[n] = s;
        }
        if (lane < 16) {
            float* dst = partial + (size_t)(bi * 2 + wr) * N_TOT;
            #pragma unroll
            for (int n = 0; n < 4; n++)
                dst[colbase + n * 16] = csum[n];
        }
    }
}

// ---------------------------------------------------------------------------
// Kernel 3: per-row sum of 128 partials -> log(negsum+eps). Grid 128 blocks,
// each block = 64 rows; wave w sums slots [w*32, w*32+32).
// ---------------------------------------------------------------------------
__global__ __launch_bounds__(256) void rowlog_kernel(const float* __restrict__ partial,
                                                     float* __restrict__ logPart) {
    const int lane = threadIdx.x & 63;
    const int w    = threadIdx.x >> 6;
    const int row  = blockIdx.x * 64 + lane;
    float s = 0.f;
    #pragma unroll 8
    for (int p = w * 32; p < w * 32 + 32; p++) s += partial[(size_t)p * N_TOT + row];
    __shared__ float red[4][64];
    red[w][lane] = s;
    __syncthreads();
    if (w == 0) {
        float tot = red[0][lane] + red[1][lane] + red[2][lane] + red[3][lane];
        float v = logf(tot + 1e-8f);
        #pragma unroll
        for (int off = 1; off < 64; off <<= 1) v += __shfl_xor(v, off);
        if (lane == 0) logPart[blockIdx.x] = v;
    }
}

// ---------------------------------------------------------------------------
// Kernel 4: final scalar: loss = mean(log terms) - 2*sum(dots)/BSZ
// ---------------------------------------------------------------------------
__global__ __launch_bounds__(256) void final_kernel(const float* __restrict__ logPart,
                                                    const float* __restrict__ posPart,
                                                    float* __restrict__ out) {
    const int t = threadIdx.x;
    float ps = 0.f;
    for (int i = t; i < BSZ; i += 256) ps += posPart[i];
    float ls = (t < 128) ? logPart[t] : 0.f;
    #pragma unroll
    for (int off = 1; off < 64; off <<= 1) {
        ps += __shfl_xor(ps, off);
        ls += __shfl_xor(ls, off);
    }
    __shared__ float redp[4], redl[4];
    const int lane = t & 63, wid = t >> 6;
    if (lane == 0) { redp[wid] = ps; redl[wid] = ls; }
    __syncthreads();
    if (t == 0) {
        const float posSum = redp[0] + redp[1] + redp[2] + redp[3];
        const float logSum = redl[0] + redl[1] + redl[2] + redl[3];
        out[0] = logSum / (float)N_TOT - 2.0f * posSum / (float)BSZ;
    }
}

extern "C" void kernel_launch(void* const* d_in, const int* in_sizes, int n_in,
                              void* d_out, int out_size, void* d_ws, size_t ws_size,
                              hipStream_t stream) {
    const float* zi = (const float*)d_in[0];
    const float* zj = (const float*)d_in[1];
    float* out = (float*)d_out;

    char* ws = (char*)d_ws;
    unsigned short* zb = (unsigned short*)ws;                    // 8192*256*2 = 4 MB
    float* partial     = (float*)(ws + (size_t)(4 << 20));       // 128*8192*4 = 4 MB
    float* logPart     = (float*)(ws + (size_t)(8 << 20));       // 128 floats
    float* posPart     = (float*)(ws + (size_t)(8 << 20) + 4096);// 4096 floats

    norm_kernel<<<2048, 256, 0, stream>>>(zi, zj, zb, posPart);
    sim_kernel<<<2080, 256, 0, stream>>>(zb, partial);
    rowlog_kernel<<<128, 256, 0, stream>>>(partial, logPart);
    final_kernel<<<1, 256, 0, stream>>>(logPart, posPart, out);
}

// Round 4
// 45.034 us; speedup vs baseline: 1.4856x; 1.1377x over previous
//
#include <hip/hip_runtime.h>

#define N_TOT 8192
#define BSZ   4096
#define DIM   256

typedef __attribute__((ext_vector_type(8))) short bf16x8;
typedef __attribute__((ext_vector_type(4))) float f32x4;

// zb is pre-scaled by sqrt(2*log2(e)) so that acc = 2*log2(e)*sim and
// exp(2*sim) == exp2(acc) with no extra multiplies in the epilogue.
#define PRESCALE 1.69864362f

__device__ __forceinline__ unsigned short f2bf(float f) {
    unsigned int u = __builtin_bit_cast(unsigned int, f);
    u = (u + 0x7fffu + ((u >> 16) & 1u)) >> 16;   // round-to-nearest-even
    return (unsigned short)u;
}

__device__ __forceinline__ void async_copy16(const void* g, void* l) {
    __builtin_amdgcn_global_load_lds((const __attribute__((address_space(1))) void*)g,
                                     (__attribute__((address_space(3))) void*)l,
                                     16, 0, 0);
}

// ---------------------------------------------------------------------------
// Kernel 1: L2-normalize rows of zi/zj -> bf16 zb[8192][256] (scaled by
// PRESCALE); fused positive-pair dots in fp32 (unscaled).
// ---------------------------------------------------------------------------
__global__ __launch_bounds__(256) void norm_kernel(const float* __restrict__ zi,
                                                   const float* __restrict__ zj,
                                                   unsigned short* __restrict__ zb,
                                                   float* __restrict__ posPart) {
    __shared__ float buf[2][256];
    const int wid  = threadIdx.x >> 6;
    const int lane = threadIdx.x & 63;
    const int pair = blockIdx.x * 2 + (wid & 1);    // 0..4095
    const bool isZj = (wid >= 2);
    const float* src = isZj ? (zj + (size_t)pair * DIM) : (zi + (size_t)pair * DIM);
    float4 v = ((const float4*)src)[lane];
    float ss = v.x * v.x + v.y * v.y + v.z * v.z + v.w * v.w;
    #pragma unroll
    for (int off = 1; off < 64; off <<= 1) ss += __shfl_xor(ss, off);
    float inv = 1.0f / fmaxf(sqrtf(ss), 1e-12f);
    float4 nv = make_float4(v.x * inv, v.y * inv, v.z * inv, v.w * inv);

    const int outRow = isZj ? (pair + BSZ) : pair;
    ushort4 o;
    o.x = f2bf(nv.x * PRESCALE); o.y = f2bf(nv.y * PRESCALE);
    o.z = f2bf(nv.z * PRESCALE); o.w = f2bf(nv.w * PRESCALE);
    ((ushort4*)(zb + (size_t)outRow * DIM))[lane] = o;

    if (!isZj) ((float4*)&buf[wid & 1][0])[lane] = nv;
    __syncthreads();
    if (isZj) {
        float4 a = ((float4*)&buf[wid & 1][0])[lane];
        float d = a.x * nv.x + a.y * nv.y + a.z * nv.z + a.w * nv.w;
        #pragma unroll
        for (int off = 1; off < 64; off <<= 1) d += __shfl_xor(d, off);
        if (lane == 0) posPart[pair] = d;
    }
}

// ---------------------------------------------------------------------------
// Kernel 2: symmetric fused Z*Z^T -> exp2 -> partial row AND col sums.
// Upper-triangular blocks (bi <= bj): 2080 blocks, 128x128 tile, BK=32,
// double-buffered (LDS 32 KB -> ~4 blocks/CU), 8 K-iters, counted vmcnt(4).
//
// LDS layout per tile (8 KB): row-pairs packed into 128 B rows.
//   chunk(16B) for (row r, k-chunk q in 0..3): pair=r>>1,
//   slot = ((r&1)*4 + q) ^ (pair & 7); byte = pair*128 + slot*16.
// Staging is linear-dest gload_lds; the source address applies the inverse
// (same involution) permutation. ds_read_b128 hits each 16B slot with
// exactly 2 lanes -> conflict-free.
// ---------------------------------------------------------------------------
__global__ __launch_bounds__(256, 4) void sim_kernel(const unsigned short* __restrict__ zb,
                                                     float* __restrict__ partial) {
    __shared__ alignas(16) char smem[32768];   // [buf][A|B] tiles; reused as f32 scratch

    const int t    = threadIdx.x;
    const int lane = t & 63;
    const int wid  = t >> 6;
    const int wr   = wid >> 1;     // 0..1
    const int wc   = wid & 1;      // 0..1

    // decode upper-triangular (bi, bj), bi <= bj, from linear block id
    const int k = blockIdx.x;                       // 0..2079
    int bi = (int)((129.0f - sqrtf(16641.0f - 8.0f * (float)k)) * 0.5f);
    while (bi * 64 - bi * (bi - 1) / 2 > k) bi--;
    while ((bi + 1) * 64 - (bi + 1) * bi / 2 <= k) bi++;
    const int bj = bi + (k - (bi * 64 - bi * (bi - 1) / 2));
    const bool diag = (bi == bj);

    const int row0 = bi * 128;
    const int col0 = bj * 128;

    f32x4 acc[4][4];
    #pragma unroll
    for (int m = 0; m < 4; m++)
        #pragma unroll
        for (int n = 0; n < 4; n++) acc[m][n] = (f32x4){0.f, 0.f, 0.f, 0.f};

    // stage one BK=32 K-tile (A and B) into buffer `b`: 4 gload_lds / thread
    #define STAGE(b, kt) do {                                                   \
        _Pragma("unroll")                                                       \
        for (int i = 0; i < 2; i++) {                                           \
            const int s   = i * 256 + t;       /* linear 16B chunk 0..511 */    \
            const int pr_ = s >> 3;            /* LDS pair row */               \
            const int c_  = (s & 7) ^ (pr_ & 7);                                \
            const int r_  = pr_ * 2 + (c_ >> 2);   /* tile row 0..127 */        \
            const int q_  = c_ & 3;            /* 16B k-chunk */                \
            char* ldsbase = smem + (b) * 16384 + (i * 256 + wid * 64) * 16;     \
            async_copy16(zb + (size_t)(row0 + r_) * DIM + (kt) * 32 + q_ * 8,   \
                         ldsbase);                                              \
            async_copy16(zb + (size_t)(col0 + r_) * DIM + (kt) * 32 + q_ * 8,   \
                         ldsbase + 8192);                                       \
        } } while (0)

    STAGE(0, 0);   // prologue

    #pragma unroll
    for (int kt = 0; kt < 8; ++kt) {
        const int cur = kt & 1;
        if (kt < 7) {
            STAGE(cur ^ 1, kt + 1);
            asm volatile("s_waitcnt vmcnt(4)" ::: "memory");  // tile kt landed
        } else {
            asm volatile("s_waitcnt vmcnt(0)" ::: "memory");
        }
        __builtin_amdgcn_sched_barrier(0);
        __builtin_amdgcn_s_barrier();

        const char* Ab = smem + cur * 16384;
        const char* Bb = Ab + 8192;
        const int q = lane >> 4;
        bf16x8 af[4], bfr[4];
        #pragma unroll
        for (int m = 0; m < 4; m++) {
            const int rr  = wr * 64 + m * 16 + (lane & 15);
            const int pr_ = rr >> 1;
            const int sl_ = (((rr & 1) << 2) | q) ^ (pr_ & 7);
            af[m] = *(const bf16x8*)(Ab + pr_ * 128 + sl_ * 16);
        }
        #pragma unroll
        for (int n = 0; n < 4; n++) {
            const int rr  = wc * 64 + n * 16 + (lane & 15);
            const int pr_ = rr >> 1;
            const int sl_ = (((rr & 1) << 2) | q) ^ (pr_ & 7);
            bfr[n] = *(const bf16x8*)(Bb + pr_ * 128 + sl_ * 16);
        }
        #pragma unroll
        for (int m = 0; m < 4; m++)
            #pragma unroll
            for (int n = 0; n < 4; n++)
                acc[m][n] = __builtin_amdgcn_mfma_f32_16x16x32_bf16(af[m], bfr[n], acc[m][n], 0, 0, 0);

        __builtin_amdgcn_sched_barrier(0);
        __builtin_amdgcn_s_barrier();   // buf[cur] free for overwrite next iter
    }
    #undef STAGE

    // ---- epilogue: exp2(acc); row sums (always) + col sums (off-diag) ----
    float rsum[4][4];
    float csum[4];
    #pragma unroll
    for (int m = 0; m < 4; m++)
        #pragma unroll
        for (int j = 0; j < 4; j++) rsum[m][j] = 0.f;
    #pragma unroll
    for (int n = 0; n < 4; n++) csum[n] = 0.f;

    const int g       = lane >> 4;
    const int c15     = lane & 15;
    const int colbase = col0 + wc * 64 + c15;
    const int rowbase = row0 + wr * 64 + (g << 2);
    #pragma unroll
    for (int m = 0; m < 4; m++) {
        #pragma unroll
        for (int n = 0; n < 4; n++) {
            const int colg = colbase + n * 16;
            #pragma unroll
            for (int j = 0; j < 4; j++) {
                const int rowg = rowbase + m * 16 + j;
                float e = exp2f(acc[m][n][j]);
                if (diag && rowg == colg) e = 0.0f;
                rsum[m][j] += e;
                csum[n] += e;
            }
        }
    }

    // col sums: reduce over the 4 row-groups; coalesced 16-lane stores
    if (!diag) {
        #pragma unroll
        for (int n = 0; n < 4; n++) {
            float s = csum[n];
            s += __shfl_xor(s, 16);
            s += __shfl_xor(s, 32);
            csum[n] = s;
        }
        if (lane < 16) {
            float* dst = partial + (size_t)(bi * 2 + wr) * N_TOT;
            #pragma unroll
            for (int n = 0; n < 4; n++)
                dst[colbase + n * 16] = csum[n];
        }
    }

    // row sums: LDS transpose (pad 20 words) -> coalesced 64-lane store.
    // Safe to reuse smem: the loop's final s_barrier means every wave's
    // ds_reads of the tiles are complete.
    float* sw = (float*)smem + wid * 1280;        // per-wave [64][20] f32
    #pragma unroll
    for (int m = 0; m < 4; m++)
        #pragma unroll
        for (int j = 0; j < 4; j++)
            sw[(m * 16 + (g << 2) + j) * 20 + c15] = rsum[m][j];

    f32x4 v0 = *(const f32x4*)(sw + lane * 20 + 0);
    f32x4 v1 = *(const f32x4*)(sw + lane * 20 + 4);
    f32x4 v2 = *(const f32x4*)(sw + lane * 20 + 8);
    f32x4 v3 = *(const f32x4*)(sw + lane * 20 + 12);
    float tot = (v0[0] + v0[1] + v0[2] + v0[3]) + (v1[0] + v1[1] + v1[2] + v1[3])
              + (v2[0] + v2[1] + v2[2] + v2[3]) + (v3[0] + v3[1] + v3[2] + v3[3]);
    partial[(size_t)(bj * 2 + wc) * N_TOT + row0 + wr * 64 + lane] = tot;
}

// ---------------------------------------------------------------------------
// Kernel 3: per-row sum of 128 partials -> log(negsum+eps). Grid 128 blocks,
// each block = 64 rows; wave w sums slots [w*32, w*32+32).
// ---------------------------------------------------------------------------
__global__ __launch_bounds__(256) void rowlog_kernel(const float* __restrict__ partial,
                                                     float* __restrict__ logPart) {
    const int lane = threadIdx.x & 63;
    const int w    = threadIdx.x >> 6;
    const int row  = blockIdx.x * 64 + lane;
    float s = 0.f;
    #pragma unroll 8
    for (int p = w * 32; p < w * 32 + 32; p++) s += partial[(size_t)p * N_TOT + row];
    __shared__ float red[4][64];
    red[w][lane] = s;
    __syncthreads();
    if (w == 0) {
        float tot = red[0][lane] + red[1][lane] + red[2][lane] + red[3][lane];
        float v = logf(tot + 1e-8f);
        #pragma unroll
        for (int off = 1; off < 64; off <<= 1) v += __shfl_xor(v, off);
        if (lane == 0) logPart[blockIdx.x] = v;
    }
}

// ---------------------------------------------------------------------------
// Kernel 4: final scalar: loss = mean(log terms) - 2*sum(dots)/BSZ
// ---------------------------------------------------------------------------
__global__ __launch_bounds__(256) void final_kernel(const float* __restrict__ logPart,
                                                    const float* __restrict__ posPart,
                                                    float* __restrict__ out) {
    const int t = threadIdx.x;
    float ps = 0.f;
    for (int i = t; i < BSZ; i += 256) ps += posPart[i];
    float ls = (t < 128) ? logPart[t] : 0.f;
    #pragma unroll
    for (int off = 1; off < 64; off <<= 1) {
        ps += __shfl_xor(ps, off);
        ls += __shfl_xor(ls, off);
    }
    __shared__ float redp[4], redl[4];
    const int lane = t & 63, wid = t >> 6;
    if (lane == 0) { redp[wid] = ps; redl[wid] = ls; }
    __syncthreads();
    if (t == 0) {
        const float posSum = redp[0] + redp[1] + redp[2] + redp[3];
        const float logSum = redl[0] + redl[1] + redl[2] + redl[3];
        out[0] = logSum / (float)N_TOT - 2.0f * posSum / (float)BSZ;
    }
}

extern "C" void kernel_launch(void* const* d_in, const int* in_sizes, int n_in,
                              void* d_out, int out_size, void* d_ws, size_t ws_size,
                              hipStream_t stream) {
    const float* zi = (const float*)d_in[0];
    const float* zj = (const float*)d_in[1];
    float* out = (float*)d_out;

    char* ws = (char*)d_ws;
    unsigned short* zb = (unsigned short*)ws;                    // 8192*256*2 = 4 MB
    float* partial     = (float*)(ws + (size_t)(4 << 20));       // 128*8192*4 = 4 MB
    float* logPart     = (float*)(ws + (size_t)(8 << 20));       // 128 floats
    float* posPart     = (float*)(ws + (size_t)(8 << 20) + 4096);// 4096 floats

    norm_kernel<<<2048, 256, 0, stream>>>(zi, zj, zb, posPart);
    sim_kernel<<<2080, 256, 0, stream>>>(zb, partial);
    rowlog_kernel<<<128, 256, 0, stream>>>(partial, logPart);
    final_kernel<<<1, 256, 0, stream>>>(logPart, posPart, out);
}